// Round 13
// baseline (73.181 us; speedup 1.0000x reference)
//
#include <hip/hip_runtime.h>
#include <stdint.h>

#define NROWS 8192
#define DDIM 256
#define NPIDS 5532
#define NCQ 5000
#define LCOLS 10532            // NPIDS + NCQ
#define IGNORE_IDX 5554
#define NT 83                  // ceil(10532/128)
#define LPAD (NT * 128)        // 10624
#define NSPLIT 8
#define NPARTS (NSPLIT * 2)    // 16 partial slots per row
#define PADCOLS (LPAD - LCOLS) // 92, each contributes exp2(0)=1 exactly
#define TSTEP (NSPLIT * 65536) // 524288 B between consecutive tiles of a split
#define OIM_SCALE 30.0f
#define LOG2E 1.4426950408889634f
#define LN2f 0.6931471805599453f

using f32x4 = __attribute__((ext_vector_type(4))) float;
using bf16x8 = __attribute__((ext_vector_type(8))) __bf16;
using ushort8 = __attribute__((ext_vector_type(8))) unsigned short;

// ws layout (bytes)
#define WS_INBF 0u             // 8192*256*2   = 4,194,304 (frag-order bf16)
#define WS_BANK 4194304u       // 10624*256*2  = 5,439,488 (frag-order, rse-scaled)
#define WS_PARTS 9633792u      // 16*8192*4    = 524,288
#define WS_RLOGIT 10158080u    // 8192*4       = 32,768
#define WS_BLK 10190848u       // 32*2*4       = 256
#define WS_NEED 10191104u

__device__ __forceinline__ unsigned short f2bf(float f) {
  union { float f; uint32_t u; } v; v.f = f;
  uint32_t u = v.u;
  uint32_t r = (u + 0x7FFFu + ((u >> 16) & 1u)) >> 16;  // RNE
  return (unsigned short)r;
}

__device__ __forceinline__ void async16(const void* g, void* l) {
  __builtin_amdgcn_global_load_lds(
      (const __attribute__((address_space(1))) uint32_t*)g,
      (__attribute__((address_space(3))) uint32_t*)l, 16, 0, 0);
}

// ---------------------------------------------------------------------------
// prep (unchanged, proven): store A and B in MFMA fragment-consumption order
// so every main-loop operand transfer is ONE coalesced 1KB op:
//   A byte(R,k)  = (R>>4)*8192 + (k>>5)*1024 + ((k>>3)&3)*256 + (R&15)*16
//   B byte(R,k)  = (R>>7)*65536 + ((R>>4)&7)*8192 + (k>>5)*1024
//                  + ((k>>3)&3)*256 + (R&15)*16
// B row R scaled by 30*rel[R]*log2e BEFORE bf16 quantization; pad rows = 0.
// ---------------------------------------------------------------------------
__global__ void prep_kernel(const float* __restrict__ inputs,
                            const float* __restrict__ lut,
                            const float* __restrict__ cq,
                            const float* __restrict__ rel,
                            unsigned short* __restrict__ in2,
                            unsigned short* __restrict__ bank3) {
  const int GIN = NROWS * (DDIM / 8);   // 262144 dst granules (16B)
  const int GBK = LPAD * (DDIM / 8);    // 339968 dst granules
  const int total = GIN + GBK;
  for (int d = blockIdx.x * blockDim.x + threadIdx.x; d < total;
       d += gridDim.x * blockDim.x) {
    const float* src = nullptr;
    unsigned short* dst;
    float scale = 1.0f;
    bool zero = false;
    if (d < GIN) {
      const int R = ((d >> 9) << 4) | (d & 15);
      const int c8 = (((d >> 6) & 7) << 2) | ((d >> 4) & 3);
      src = inputs + R * DDIM + c8 * 8;
      dst = in2 + (size_t)d * 8;
    } else {
      const int b = d - GIN;
      const int R = ((b >> 12) << 7) | (((b >> 9) & 7) << 4) | (b & 15);
      const int c8 = (((b >> 6) & 7) << 2) | ((b >> 4) & 3);
      dst = bank3 + (size_t)b * 8;
      if (R < NPIDS) src = lut + (size_t)R * DDIM + c8 * 8;
      else if (R < LCOLS) src = cq + (size_t)(R - NPIDS) * DDIM + c8 * 8;
      else zero = true;
      if (!zero) scale = OIM_SCALE * LOG2E * rel[R];
    }
    ushort8 o = {0, 0, 0, 0, 0, 0, 0, 0};
    if (!zero) {
      const f32x4* s4 = (const f32x4*)src;
      f32x4 v0 = s4[0], v1 = s4[1];
      o[0] = f2bf(v0[0] * scale); o[1] = f2bf(v0[1] * scale);
      o[2] = f2bf(v0[2] * scale); o[3] = f2bf(v0[3] * scale);
      o[4] = f2bf(v1[0] * scale); o[5] = f2bf(v1[1] * scale);
      o[6] = f2bf(v1[2] * scale); o[7] = f2bf(v1[3] * scale);
    }
    *(ushort8*)dst = o;
  }
}

// ---------------------------------------------------------------------------
// main: fused GEMM + sum-of-exp. r10 geometry (256 blocks, 512 thr = 8 waves
// 4x2, BM=256, wave tile 64x64, A reg-persistent) + m201-style fine pipeline:
//  - 5-slot x 16KB LDS ring, stage depth 3 (phase Q issues stage Q+3)
//  - per phase: vmcnt(2) [stage Q+1 landed, issued 2 phases ago] -> barrier
//    -> STG(Q+3) -> ds_read frags(Q+1) into idle bank -> lgkmcnt(8)
//    -> 32 MFMA on frags(Q) read LAST phase (ds latency hidden)
//  - tile-end exp2 epilogue interleaved into phase 3's kl=1 MFMA stream
//    (exp2 frag finished 3 MFMAs earlier -> issues in the MFMA shadow)
// Unified regs ~224/wave (aR 128 + bA/bB 64 + acc 64 AGPR shared file) fits
// the 2-waves/SIMD 256 cap; 2 blocks/CU is impossible with reg-persistent A
// (r12 lesson), so all hiding is within-wave/within-phase.
// ---------------------------------------------------------------------------
#define STG()                                                             \
  do {                                                                    \
    char* _d = ring + roS + tid * 16;                                     \
    async16(sgP, _d);                                                     \
    async16(sgP + 32768, _d + 8192);                                      \
    roS += 16384; if (roS == 81920) roS = 0;                              \
  } while (0)

#define DSREAD8(BANK, RO)                                                 \
  do {                                                                    \
    const char* _p = rB + (RO);                                           \
    _Pragma("unroll") for (int _f = 0; _f < 8; ++_f)                      \
      BANK[_f] =                                                          \
          *(const bf16x8*)(_p + (_f >> 1) * 2048 + (_f & 1) * 1024);      \
  } while (0)

#define CLUSTERN(PP, BC)                                                  \
  do {                                                                    \
    _Pragma("unroll") for (int _kl = 0; _kl < 2; ++_kl)                   \
      _Pragma("unroll") for (int _mi = 0; _mi < 4; ++_mi)                 \
        _Pragma("unroll") for (int _ni = 0; _ni < 4; ++_ni)               \
          acc[_mi][_ni] = __builtin_amdgcn_mfma_f32_16x16x32_bf16(        \
              aR[_mi][(PP) * 2 + _kl], BC[_ni * 2 + _kl],                 \
              ((PP) == 0 && _kl == 0) ? vzero : acc[_mi][_ni], 0, 0, 0);  \
  } while (0)

// phase 3: kl=0 plain; kl=1 with tile epilogue interleaved (distance-3)
#define CLUSTER3(BC)                                                      \
  do {                                                                    \
    _Pragma("unroll") for (int _mi = 0; _mi < 4; ++_mi)                   \
      _Pragma("unroll") for (int _ni = 0; _ni < 4; ++_ni)                 \
        acc[_mi][_ni] = __builtin_amdgcn_mfma_f32_16x16x32_bf16(          \
            aR[_mi][6], BC[_ni * 2], acc[_mi][_ni], 0, 0, 0);             \
    _Pragma("unroll") for (int _i = 0; _i < 16; ++_i) {                   \
      const int _mi = _i >> 2, _ni = _i & 3;                              \
      acc[_mi][_ni] = __builtin_amdgcn_mfma_f32_16x16x32_bf16(            \
          aR[_mi][7], BC[_ni * 2 + 1], acc[_mi][_ni], 0, 0, 0);           \
      if (_i >= 3) {                                                      \
        const int _pm = (_i - 3) >> 2, _pn = (_i - 3) & 3;                \
        _Pragma("unroll") for (int _r = 0; _r < 4; ++_r)                  \
          se[_pm][_r] += __builtin_amdgcn_exp2f(acc[_pm][_pn][_r]);       \
      }                                                                   \
    }                                                                     \
    _Pragma("unroll") for (int _p = 13; _p < 16; ++_p) {                  \
      const int _pm = _p >> 2, _pn = _p & 3;                              \
      _Pragma("unroll") for (int _r = 0; _r < 4; ++_r)                    \
        se[_pm][_r] += __builtin_amdgcn_exp2f(acc[_pm][_pn][_r]);         \
    }                                                                     \
  } while (0)

#define PHN(PP, BC, BN)                                                   \
  do {                                                                    \
    asm volatile("s_waitcnt vmcnt(2)" ::: "memory");                      \
    asm volatile("s_barrier" ::: "memory");                               \
    STG();                                                                \
    sgP += ((PP) == 0) ? (TSTEP - 6144) : 2048;                           \
    DSREAD8(BN, roN);                                                     \
    roN += 16384; if (roN == 81920) roN = 0;                              \
    asm volatile("s_waitcnt lgkmcnt(8)" ::: "memory");                    \
    __builtin_amdgcn_sched_barrier(0);                                    \
    __builtin_amdgcn_s_setprio(1);                                        \
    if ((PP) == 3) { CLUSTER3(BC); } else { CLUSTERN(PP, BC); }           \
    __builtin_amdgcn_s_setprio(0);                                        \
  } while (0)

__global__ __launch_bounds__(512, 1) void oim_main_kernel(
    const unsigned short* __restrict__ in2,
    const unsigned short* __restrict__ bank3,
    float* __restrict__ parts) {
  extern __shared__ char ring[];  // 81920 = 5 slots x 16KB
  const int tid = threadIdx.x;
  const int lane = tid & 63;
  const int wv = tid >> 6;    // 0..7
  const int wrow = wv >> 1;   // 0..3
  const int wcol = wv & 1;    // 0..1
  const int ql = lane & 15;
  const int h = lane >> 4;    // 0..3

  const int bid = blockIdx.x;
  const int sp = bid & 7;     // == XCD id under round-robin dispatch
  const int bm = bid >> 3;    // 0..31 (256-row blocks)
  const int ntiles = (sp < 3) ? 11 : 10;  // 3*11 + 5*10 = 83

  // ---- A fragments -> registers (32 coalesced dwordx4, once) ----
  bf16x8 aR[4][8];
  {
    const char* ab =
        (const char*)in2 + (size_t)(bm * 16 + wrow * 4) * 8192 + lane * 16;
#pragma unroll
    for (int mi = 0; mi < 4; ++mi)
#pragma unroll
      for (int kk = 0; kk < 8; ++kk)
        aR[mi][kk] = *(const bf16x8*)(ab + mi * 8192 + kk * 1024);
  }
  const int rowb = bm * 256 + wrow * 64 + h * 4;

  asm volatile("" ::: "memory");  // pin: A-loads precede staging (vmcnt order)

  // staging: per-thread src/dst (r10 mapping, slot stride now 16384)
  const char* sgT = (const char*)bank3 + (size_t)sp * 65536 +
                    (tid >> 7) * 8192 + (tid & 127) * 16;
  // prologue: stage phases 0,1,2 -> slots 0,1,2 (6 ops in flight)
#pragma unroll
  for (int p = 0; p < 3; ++p) {
    char* d = ring + p * 16384 + tid * 16;
    async16(sgT + p * 2048, d);
    async16(sgT + p * 2048 + 32768, d + 8192);
  }
  const char* sgP = sgT + 6144;  // source of phase 3 (first loop stage)
  int roS = 49152;               // dst slot of phase 3
  int roN = 16384;               // read-ahead slot (phase 1)

  // per-wave LDS read base (its wcol 64-col strip)
  const char* rB = ring + wcol * 8192 + lane * 16;

  const f32x4 vzero = {0.f, 0.f, 0.f, 0.f};
  f32x4 acc[4][4];
  float se[4][4];
#pragma unroll
  for (int a = 0; a < 4; ++a)
#pragma unroll
    for (int b = 0; b < 4; ++b) se[a][b] = 0.f;

  // own stage(0) landed; barrier -> ALL waves' stage(0) landed; read frags(0)
  asm volatile("s_waitcnt vmcnt(4)" ::: "memory");
  asm volatile("s_barrier" ::: "memory");
  bf16x8 bA[8], bB[8];
  DSREAD8(bA, 0);

  for (int t = 0; t < ntiles - 1; ++t) {
    PHN(0, bA, bB);
    PHN(1, bB, bA);
    PHN(2, bA, bB);
    PHN(3, bB, bA);
  }
  // ---- tail tile (Q = NQ-4 .. NQ-1) ----
  PHN(0, bA, bB);  // stages NQ-1 (the final stage), reads frags(NQ-3)
  // pp1: no stage left; vmcnt(2) -> stage(NQ-2) done (only NQ-1 in flight)
  asm volatile("s_waitcnt vmcnt(2)" ::: "memory");
  asm volatile("s_barrier" ::: "memory");
  DSREAD8(bA, roN);
  roN += 16384; if (roN == 81920) roN = 0;
  asm volatile("s_waitcnt lgkmcnt(8)" ::: "memory");
  __builtin_amdgcn_sched_barrier(0);
  __builtin_amdgcn_s_setprio(1);
  CLUSTERN(1, bB);
  __builtin_amdgcn_s_setprio(0);
  // pp2: need stage(NQ-1) (the newest) -> vmcnt(0)
  asm volatile("s_waitcnt vmcnt(0)" ::: "memory");
  asm volatile("s_barrier" ::: "memory");
  DSREAD8(bB, roN);
  asm volatile("s_waitcnt lgkmcnt(8)" ::: "memory");
  __builtin_amdgcn_sched_barrier(0);
  __builtin_amdgcn_s_setprio(1);
  CLUSTERN(2, bA);
  __builtin_amdgcn_s_setprio(0);
  // pp3: compute + interleaved epilogue only
  asm volatile("s_waitcnt lgkmcnt(0)" ::: "memory");
  __builtin_amdgcn_sched_barrier(0);
  __builtin_amdgcn_s_setprio(1);
  CLUSTER3(bB);
  __builtin_amdgcn_s_setprio(0);

  // reduce across the 16 column-lanes (ql) of each row group
#pragma unroll
  for (int mi = 0; mi < 4; ++mi)
#pragma unroll
    for (int r = 0; r < 4; ++r) {
      float v = se[mi][r];
      v += __shfl_xor(v, 1);
      v += __shfl_xor(v, 2);
      v += __shfl_xor(v, 4);
      v += __shfl_xor(v, 8);
      se[mi][r] = v;
    }
  if (ql == 0) {
    const int part = sp * 2 + wcol;  // deterministic partial slot, 0..15
#pragma unroll
    for (int mi = 0; mi < 4; ++mi) {
      f32x4 o = {se[mi][0], se[mi][1], se[mi][2], se[mi][3]};
      *(f32x4*)(parts + (size_t)part * NROWS + rowb + mi * 16) = o;
    }
  }
}

// ---------------------------------------------------------------------------
// exact fp32 label logit: one wave per row, gather bank row by label.
// ---------------------------------------------------------------------------
__global__ void label_logit_kernel(const float* __restrict__ inputs,
                                   const int* __restrict__ label,
                                   const float* __restrict__ lut,
                                   const float* __restrict__ cq,
                                   const float* __restrict__ rel,
                                   float* __restrict__ rowlogit) {
  const int lane = threadIdx.x & 63;
  const int wv = threadIdx.x >> 6;
  const int row = blockIdx.x * 4 + wv;
  if (row >= NROWS) return;
  const int l = label[row];
  float out = 0.0f;
  if (l != IGNORE_IDX && l >= 0 && l < LCOLS) {
    const float* bk = (l < NPIDS) ? (lut + (size_t)l * DDIM)
                                  : (cq + (size_t)(l - NPIDS) * DDIM);
    f32x4 a = *(const f32x4*)(inputs + (size_t)row * DDIM + lane * 4);
    f32x4 b = *(const f32x4*)(bk + lane * 4);
    float d = a[0] * b[0] + a[1] * b[1] + a[2] * b[2] + a[3] * b[3];
#pragma unroll
    for (int m = 1; m < 64; m <<= 1) d += __shfl_xor(d, m);
    out = OIM_SCALE * rel[l] * d;
  }
  if (lane == 0) rowlogit[row] = out;
}

// ---------------------------------------------------------------------------
// reduce1: 32 blocks x 256 threads, one row per thread.
// tot = sum(parts) - PADCOLS; s = ln2*log2(tot) - rowlogit for valid rows.
// ---------------------------------------------------------------------------
__global__ void reduce1_kernel(const float* __restrict__ parts,
                               const float* __restrict__ rowlogit,
                               const int* __restrict__ label,
                               float* __restrict__ blk) {
  const int r = blockIdx.x * 256 + threadIdx.x;
  float s = 0.0f, c = 0.0f;
  if (label[r] != IGNORE_IDX) {
    float tot = 0.0f;
#pragma unroll
    for (int p = 0; p < NPARTS; ++p) tot += parts[p * NROWS + r];
    tot -= (float)PADCOLS;
    s = LN2f * __builtin_log2f(tot) - rowlogit[r];
    c = 1.0f;
  }
#pragma unroll
  for (int m = 1; m < 64; m <<= 1) {
    s += __shfl_xor(s, m);
    c += __shfl_xor(c, m);
  }
  __shared__ float ss[4], sc[4];
  const int wv = threadIdx.x >> 6, lane = threadIdx.x & 63;
  if (lane == 0) { ss[wv] = s; sc[wv] = c; }
  __syncthreads();
  if (threadIdx.x == 0) {
    blk[blockIdx.x * 2 + 0] = ss[0] + ss[1] + ss[2] + ss[3];
    blk[blockIdx.x * 2 + 1] = sc[0] + sc[1] + sc[2] + sc[3];
  }
}

__global__ void reduce2_kernel(const float* __restrict__ blk,
                               float* __restrict__ out) {
  const int lane = threadIdx.x;
  float s = (lane < 32) ? blk[lane * 2 + 0] : 0.0f;
  float c = (lane < 32) ? blk[lane * 2 + 1] : 0.0f;
#pragma unroll
  for (int m = 1; m < 32; m <<= 1) {
    s += __shfl_xor(s, m);
    c += __shfl_xor(c, m);
  }
  if (lane == 0) out[0] = s / fmaxf(c, 1.0f);
}

extern "C" void kernel_launch(void* const* d_in, const int* in_sizes, int n_in,
                              void* d_out, int out_size, void* d_ws,
                              size_t ws_size, hipStream_t stream) {
  const float* inputs = (const float*)d_in[0];
  const int* label = (const int*)d_in[1];
  // d_in[2] = ious (unused by the reference loss)
  const float* lut = (const float*)d_in[3];
  const float* cq = (const float*)d_in[4];
  const float* rel = (const float*)d_in[5];
  float* out = (float*)d_out;
  char* ws = (char*)d_ws;
  if (ws_size < WS_NEED) return;

  unsigned short* in2 = (unsigned short*)(ws + WS_INBF);
  unsigned short* bank3 = (unsigned short*)(ws + WS_BANK);
  float* parts = (float*)(ws + WS_PARTS);
  float* rowlogit = (float*)(ws + WS_RLOGIT);
  float* blk = (float*)(ws + WS_BLK);

  hipFuncSetAttribute((const void*)oim_main_kernel,
                      hipFuncAttributeMaxDynamicSharedMemorySize, 81920);

  prep_kernel<<<dim3(1024), dim3(256), 0, stream>>>(inputs, lut, cq, rel,
                                                    in2, bank3);
  label_logit_kernel<<<dim3(2048), dim3(256), 0, stream>>>(inputs, label, lut,
                                                           cq, rel, rowlogit);
  oim_main_kernel<<<dim3(256), dim3(512), 81920, stream>>>(in2, bank3, parts);
  reduce1_kernel<<<dim3(32), dim3(256), 0, stream>>>(parts, rowlogit, label,
                                                     blk);
  reduce2_kernel<<<dim3(1), dim3(64), 0, stream>>>(blk, out);
}

// Round 14
// 62.280 us; speedup vs baseline: 1.1750x; 1.1750x over previous
//
#include <hip/hip_runtime.h>
#include <stdint.h>

#define NROWS 8192
#define DDIM 256
#define NPIDS 5532
#define NCQ 5000
#define LCOLS 10532            // NPIDS + NCQ
#define IGNORE_IDX 5554
#define NT 83                  // ceil(10532/128)
#define LPAD (NT * 128)        // 10624
#define NSPLIT 8
#define NPARTS (NSPLIT * 2)    // 16 partial slots per row
#define PADCOLS (LPAD - LCOLS) // 92, each contributes exp2(0)=1 exactly
#define TSTEP (NSPLIT * 65536) // 524288 B between consecutive tiles of a split
#define OIM_SCALE 30.0f
#define LOG2E 1.4426950408889634f
#define LN2f 0.6931471805599453f

using f32x4 = __attribute__((ext_vector_type(4))) float;
using bf16x8 = __attribute__((ext_vector_type(8))) __bf16;
using ushort8 = __attribute__((ext_vector_type(8))) unsigned short;

// ws layout (bytes)
#define WS_INBF 0u             // 8192*256*2   = 4,194,304 (frag-order bf16)
#define WS_BANK 4194304u       // 10624*256*2  = 5,439,488 (frag-order, rse-scaled)
#define WS_PARTS 9633792u      // 16*8192*4    = 524,288
#define WS_RLOGIT 10158080u    // 8192*4       = 32,768
#define WS_BLK 10190848u       // 32*2*4       = 256
#define WS_NEED 10191104u

__device__ __forceinline__ unsigned short f2bf(float f) {
  union { float f; uint32_t u; } v; v.f = f;
  uint32_t u = v.u;
  uint32_t r = (u + 0x7FFFu + ((u >> 16) & 1u)) >> 16;  // RNE
  return (unsigned short)r;
}

__device__ __forceinline__ void async16(const void* g, void* l) {
  __builtin_amdgcn_global_load_lds(
      (const __attribute__((address_space(1))) uint32_t*)g,
      (__attribute__((address_space(3))) uint32_t*)l, 16, 0, 0);
}

// ---------------------------------------------------------------------------
// prep (unchanged, proven): store A and B in MFMA fragment-consumption order
// so every main-loop operand transfer is ONE coalesced 1KB op:
//   A byte(R,k)  = (R>>4)*8192 + (k>>5)*1024 + ((k>>3)&3)*256 + (R&15)*16
//   B byte(R,k)  = (R>>7)*65536 + ((R>>4)&7)*8192 + (k>>5)*1024
//                  + ((k>>3)&3)*256 + (R&15)*16
// B row R scaled by 30*rel[R]*log2e BEFORE bf16 quantization; pad rows = 0.
// ---------------------------------------------------------------------------
__global__ void prep_kernel(const float* __restrict__ inputs,
                            const float* __restrict__ lut,
                            const float* __restrict__ cq,
                            const float* __restrict__ rel,
                            unsigned short* __restrict__ in2,
                            unsigned short* __restrict__ bank3) {
  const int GIN = NROWS * (DDIM / 8);   // 262144 dst granules (16B)
  const int GBK = LPAD * (DDIM / 8);    // 339968 dst granules
  const int total = GIN + GBK;
  for (int d = blockIdx.x * blockDim.x + threadIdx.x; d < total;
       d += gridDim.x * blockDim.x) {
    const float* src = nullptr;
    unsigned short* dst;
    float scale = 1.0f;
    bool zero = false;
    if (d < GIN) {
      const int R = ((d >> 9) << 4) | (d & 15);
      const int c8 = (((d >> 6) & 7) << 2) | ((d >> 4) & 3);
      src = inputs + R * DDIM + c8 * 8;
      dst = in2 + (size_t)d * 8;
    } else {
      const int b = d - GIN;
      const int R = ((b >> 12) << 7) | (((b >> 9) & 7) << 4) | (b & 15);
      const int c8 = (((b >> 6) & 7) << 2) | ((b >> 4) & 3);
      dst = bank3 + (size_t)b * 8;
      if (R < NPIDS) src = lut + (size_t)R * DDIM + c8 * 8;
      else if (R < LCOLS) src = cq + (size_t)(R - NPIDS) * DDIM + c8 * 8;
      else zero = true;
      if (!zero) scale = OIM_SCALE * LOG2E * rel[R];
    }
    ushort8 o = {0, 0, 0, 0, 0, 0, 0, 0};
    if (!zero) {
      const f32x4* s4 = (const f32x4*)src;
      f32x4 v0 = s4[0], v1 = s4[1];
      o[0] = f2bf(v0[0] * scale); o[1] = f2bf(v0[1] * scale);
      o[2] = f2bf(v0[2] * scale); o[3] = f2bf(v0[3] * scale);
      o[4] = f2bf(v1[0] * scale); o[5] = f2bf(v1[1] * scale);
      o[6] = f2bf(v1[2] * scale); o[7] = f2bf(v1[3] * scale);
    }
    *(ushort8*)dst = o;
  }
}

// ---------------------------------------------------------------------------
// main: fused GEMM + sum-of-exp. r10 geometry (256 blocks, 512 thr = 8 waves
// 4x2, BM=256, wave tile 64x64, A reg-persistent, 64 B/MFMA staging) with
// two register-neutral stall fixes (r13's +64-VGPR variant spilled):
//  - barrier + vmcnt every 2 PHASES (interval): ring 6 x 16KB (96KB), stage
//    pair per interval, steady vmcnt(4): at each barrier the newest 4 vmem
//    ops are last interval's stages, so this interval's data (staged 2
//    intervals ago) is landed for ALL waves. Slot reuse distance 6 > 5
//    lookahead, separated by a barrier -> no write/read race.
//  - lgkmcnt(4) split per phase: kl=0 frag reads issued first, MFMA kl=0
//    starts after 4 reads; kl=1 reads complete in its MFMA shadow.
// Unchanged: serial per-tile exp2 epilogue, XCD decode (sp=bid&7), exact
// label logit in its own kernel, deterministic partial buffers.
// ---------------------------------------------------------------------------
#define STGS()                                                            \
  do {                                                                    \
    if (S < NQ) {                                                         \
      char* _d = ring + roS + tid * 16;                                   \
      async16(sgP, _d);                                                   \
      async16(sgP + 32768, _d + 8192);                                    \
      sgP += ((S & 3) == 3) ? (TSTEP - 6144) : 2048;                      \
      roS += 16384; if (roS == 98304) roS = 0;                            \
      ++S;                                                                \
    }                                                                     \
  } while (0)

#define COMP(PP)                                                          \
  do {                                                                    \
    const char* _c = rB + roN;                                            \
    bf16x8 b0[4], b1[4];                                                  \
    _Pragma("unroll") for (int _ni = 0; _ni < 4; ++_ni)                   \
      b0[_ni] = *(const bf16x8*)(_c + _ni * 2048);                        \
    _Pragma("unroll") for (int _ni = 0; _ni < 4; ++_ni)                   \
      b1[_ni] = *(const bf16x8*)(_c + _ni * 2048 + 1024);                 \
    asm volatile("s_waitcnt lgkmcnt(4)" ::: "memory");                    \
    __builtin_amdgcn_sched_barrier(0);                                    \
    __builtin_amdgcn_s_setprio(1);                                        \
    _Pragma("unroll") for (int _mi = 0; _mi < 4; ++_mi)                   \
      _Pragma("unroll") for (int _ni = 0; _ni < 4; ++_ni)                 \
        acc[_mi][_ni] = __builtin_amdgcn_mfma_f32_16x16x32_bf16(          \
            aR[_mi][(PP) * 2], b0[_ni],                                   \
            ((PP) == 0) ? vzero : acc[_mi][_ni], 0, 0, 0);                \
    asm volatile("s_waitcnt lgkmcnt(0)" ::: "memory");                    \
    __builtin_amdgcn_sched_barrier(0);                                    \
    _Pragma("unroll") for (int _mi = 0; _mi < 4; ++_mi)                   \
      _Pragma("unroll") for (int _ni = 0; _ni < 4; ++_ni)                 \
        acc[_mi][_ni] = __builtin_amdgcn_mfma_f32_16x16x32_bf16(          \
            aR[_mi][(PP) * 2 + 1], b1[_ni], acc[_mi][_ni], 0, 0, 0);      \
    __builtin_amdgcn_s_setprio(0);                                        \
    roN += 16384; if (roN == 98304) roN = 0;                              \
  } while (0)

#define VMB(VMN)                                                          \
  do {                                                                    \
    asm volatile("s_waitcnt vmcnt(" #VMN ")" ::: "memory");               \
    asm volatile("s_barrier" ::: "memory");                               \
  } while (0)

__global__ __launch_bounds__(512, 1) void oim_main_kernel(
    const unsigned short* __restrict__ in2,
    const unsigned short* __restrict__ bank3,
    float* __restrict__ parts) {
  extern __shared__ char ring[];  // 98304 = 6 slots x 16KB
  const int tid = threadIdx.x;
  const int lane = tid & 63;
  const int wv = tid >> 6;    // 0..7
  const int wrow = wv >> 1;   // 0..3
  const int wcol = wv & 1;    // 0..1
  const int ql = lane & 15;
  const int h = lane >> 4;    // 0..3

  const int bid = blockIdx.x;
  const int sp = bid & 7;     // == XCD id under round-robin dispatch
  const int bm = bid >> 3;    // 0..31 (256-row blocks)
  const int ntiles = (sp < 3) ? 11 : 10;  // 3*11 + 5*10 = 83
  const int NQ = ntiles * 4;

  // ---- A fragments -> registers (32 coalesced dwordx4, once) ----
  bf16x8 aR[4][8];
  {
    const char* ab =
        (const char*)in2 + (size_t)(bm * 16 + wrow * 4) * 8192 + lane * 16;
#pragma unroll
    for (int mi = 0; mi < 4; ++mi)
#pragma unroll
      for (int kk = 0; kk < 8; ++kk)
        aR[mi][kk] = *(const bf16x8*)(ab + mi * 8192 + kk * 1024);
  }
  const int rowb = bm * 256 + wrow * 64 + h * 4;

  asm volatile("" ::: "memory");  // pin: A-loads precede staging (vmcnt order)

  // staging geometry (r10 mapping): src = bank + sp*65536 + colblk*8192 +
  // pp*2048 + within; colblk = tid>>7 (0-3) and +4 via src+32768.
  const char* sgT = (const char*)bank3 + (size_t)sp * 65536 +
                    (tid >> 7) * 8192 + (tid & 127) * 16;
  // prologue: stage phases 0..3 -> slots 0..3 (8 ops in flight)
#pragma unroll
  for (int p = 0; p < 4; ++p) {
    char* d = ring + p * 16384 + tid * 16;
    async16(sgT + p * 2048, d);
    async16(sgT + p * 2048 + 32768, d + 8192);
  }
  const char* sgP = sgT + TSTEP;  // next stage: S=4 (tile 1, pp 0)
  int S = 4;
  int roS = 65536;                // slot 4
  int roN = 0;

  // per-wave LDS read base (its wcol 64-col strip of 4 colblks)
  const char* rB = ring + wcol * 8192 + lane * 16;

  const f32x4 vzero = {0.f, 0.f, 0.f, 0.f};
  f32x4 acc[4][4];
  float se[4][4];
#pragma unroll
  for (int a = 0; a < 4; ++a)
#pragma unroll
    for (int b = 0; b < 4; ++b) se[a][b] = 0.f;

  for (int t = 0; t < ntiles - 1; ++t) {
    VMB(4); STGS(); STGS(); COMP(0); COMP(1);
    VMB(4); STGS(); STGS(); COMP(2); COMP(3);
    // tile epilogue: pure exp2+add (B pre-scaled by rse; pad cols -> +1.0)
#pragma unroll
    for (int mi = 0; mi < 4; ++mi)
#pragma unroll
      for (int ni = 0; ni < 4; ++ni)
#pragma unroll
        for (int r = 0; r < 4; ++r)
          se[mi][r] += __builtin_amdgcn_exp2f(acc[mi][ni][r]);
  }
  // ---- last tile: no stages left; final interval needs full drain ----
  VMB(4); COMP(0); COMP(1);
  VMB(0); COMP(2); COMP(3);
#pragma unroll
  for (int mi = 0; mi < 4; ++mi)
#pragma unroll
    for (int ni = 0; ni < 4; ++ni)
#pragma unroll
      for (int r = 0; r < 4; ++r)
        se[mi][r] += __builtin_amdgcn_exp2f(acc[mi][ni][r]);

  // reduce across the 16 column-lanes (ql) of each row group
#pragma unroll
  for (int mi = 0; mi < 4; ++mi)
#pragma unroll
    for (int r = 0; r < 4; ++r) {
      float v = se[mi][r];
      v += __shfl_xor(v, 1);
      v += __shfl_xor(v, 2);
      v += __shfl_xor(v, 4);
      v += __shfl_xor(v, 8);
      se[mi][r] = v;
    }
  if (ql == 0) {
    const int part = sp * 2 + wcol;  // deterministic partial slot, 0..15
#pragma unroll
    for (int mi = 0; mi < 4; ++mi) {
      f32x4 o = {se[mi][0], se[mi][1], se[mi][2], se[mi][3]};
      *(f32x4*)(parts + (size_t)part * NROWS + rowb + mi * 16) = o;
    }
  }
}

// ---------------------------------------------------------------------------
// exact fp32 label logit: one wave per row, gather bank row by label.
// ---------------------------------------------------------------------------
__global__ void label_logit_kernel(const float* __restrict__ inputs,
                                   const int* __restrict__ label,
                                   const float* __restrict__ lut,
                                   const float* __restrict__ cq,
                                   const float* __restrict__ rel,
                                   float* __restrict__ rowlogit) {
  const int lane = threadIdx.x & 63;
  const int wv = threadIdx.x >> 6;
  const int row = blockIdx.x * 4 + wv;
  if (row >= NROWS) return;
  const int l = label[row];
  float out = 0.0f;
  if (l != IGNORE_IDX && l >= 0 && l < LCOLS) {
    const float* bk = (l < NPIDS) ? (lut + (size_t)l * DDIM)
                                  : (cq + (size_t)(l - NPIDS) * DDIM);
    f32x4 a = *(const f32x4*)(inputs + (size_t)row * DDIM + lane * 4);
    f32x4 b = *(const f32x4*)(bk + lane * 4);
    float d = a[0] * b[0] + a[1] * b[1] + a[2] * b[2] + a[3] * b[3];
#pragma unroll
    for (int m = 1; m < 64; m <<= 1) d += __shfl_xor(d, m);
    out = OIM_SCALE * rel[l] * d;
  }
  if (lane == 0) rowlogit[row] = out;
}

// ---------------------------------------------------------------------------
// reduce1: 32 blocks x 256 threads, one row per thread.
// tot = sum(parts) - PADCOLS; s = ln2*log2(tot) - rowlogit for valid rows.
// ---------------------------------------------------------------------------
__global__ void reduce1_kernel(const float* __restrict__ parts,
                               const float* __restrict__ rowlogit,
                               const int* __restrict__ label,
                               float* __restrict__ blk) {
  const int r = blockIdx.x * 256 + threadIdx.x;
  float s = 0.0f, c = 0.0f;
  if (label[r] != IGNORE_IDX) {
    float tot = 0.0f;
#pragma unroll
    for (int p = 0; p < NPARTS; ++p) tot += parts[p * NROWS + r];
    tot -= (float)PADCOLS;
    s = LN2f * __builtin_log2f(tot) - rowlogit[r];
    c = 1.0f;
  }
#pragma unroll
  for (int m = 1; m < 64; m <<= 1) {
    s += __shfl_xor(s, m);
    c += __shfl_xor(c, m);
  }
  __shared__ float ss[4], sc[4];
  const int wv = threadIdx.x >> 6, lane = threadIdx.x & 63;
  if (lane == 0) { ss[wv] = s; sc[wv] = c; }
  __syncthreads();
  if (threadIdx.x == 0) {
    blk[blockIdx.x * 2 + 0] = ss[0] + ss[1] + ss[2] + ss[3];
    blk[blockIdx.x * 2 + 1] = sc[0] + sc[1] + sc[2] + sc[3];
  }
}

__global__ void reduce2_kernel(const float* __restrict__ blk,
                               float* __restrict__ out) {
  const int lane = threadIdx.x;
  float s = (lane < 32) ? blk[lane * 2 + 0] : 0.0f;
  float c = (lane < 32) ? blk[lane * 2 + 1] : 0.0f;
#pragma unroll
  for (int m = 1; m < 32; m <<= 1) {
    s += __shfl_xor(s, m);
    c += __shfl_xor(c, m);
  }
  if (lane == 0) out[0] = s / fmaxf(c, 1.0f);
}

extern "C" void kernel_launch(void* const* d_in, const int* in_sizes, int n_in,
                              void* d_out, int out_size, void* d_ws,
                              size_t ws_size, hipStream_t stream) {
  const float* inputs = (const float*)d_in[0];
  const int* label = (const int*)d_in[1];
  // d_in[2] = ious (unused by the reference loss)
  const float* lut = (const float*)d_in[3];
  const float* cq = (const float*)d_in[4];
  const float* rel = (const float*)d_in[5];
  float* out = (float*)d_out;
  char* ws = (char*)d_ws;
  if (ws_size < WS_NEED) return;

  unsigned short* in2 = (unsigned short*)(ws + WS_INBF);
  unsigned short* bank3 = (unsigned short*)(ws + WS_BANK);
  float* parts = (float*)(ws + WS_PARTS);
  float* rowlogit = (float*)(ws + WS_RLOGIT);
  float* blk = (float*)(ws + WS_BLK);

  hipFuncSetAttribute((const void*)oim_main_kernel,
                      hipFuncAttributeMaxDynamicSharedMemorySize, 98304);

  prep_kernel<<<dim3(1024), dim3(256), 0, stream>>>(inputs, lut, cq, rel,
                                                    in2, bank3);
  label_logit_kernel<<<dim3(2048), dim3(256), 0, stream>>>(inputs, label, lut,
                                                           cq, rel, rowlogit);
  oim_main_kernel<<<dim3(256), dim3(512), 98304, stream>>>(in2, bank3, parts);
  reduce1_kernel<<<dim3(32), dim3(256), 0, stream>>>(parts, rowlogit, label,
                                                     blk);
  reduce2_kernel<<<dim3(1), dim3(64), 0, stream>>>(blk, out);
}